// Round 5
// baseline (2258.584 us; speedup 1.0000x reference)
//
#include <hip/hip_runtime.h>
#include <hip/hip_fp16.h>
#include <math.h>

// R7: contention-free radix edge grouping. R12: fp16 gather table.
// R13: MFMA GEMM (16x16x32 f16). R14: edge-parallel bucket aggregation --
// REGRESSED 46.6 -> 682us/pass: fp32 atomicAdd on LDS compiled to a CAS
// retry loop (VALUBusy 1.65%, HBM 1.8% = spin signature; harness owns the
// flags, no -munsafe-fp-atomics).
// R15 (this round): unsafeAtomicAdd -> native ds_add_f32 (no-return HW
// atomic, IEEE add; only summation order differs). Structure already
// verified correct in R14 (absmax 9.5e-7, FETCH 82MB as designed).

#define BKT_SHIFT 7
#define BKT_NODES 128
#define EPB 8192       // edges per block in hist/group passes
#define ACC_STRIDE 65  // floats per node row in LDS accumulator

typedef _Float16 f16x8 __attribute__((ext_vector_type(8)));
typedef float f32x4 __attribute__((ext_vector_type(4)));

// ---------------- phase A: per-(bucket,block) histogram ----------------
__global__ __launch_bounds__(1024) void block_hist_kernel(
    const int* __restrict__ dst, int* __restrict__ hist, int E, int NBKT, int NBLK) {
  __shared__ int lh[1024];  // >= NBKT
  const int t = threadIdx.x;
  const int blk = blockIdx.x;
  for (int k = t; k < NBKT; k += 1024) lh[k] = 0;
  __syncthreads();
  const int e0 = blk * EPB;
  const int e1 = min(e0 + EPB, E);
  for (int e = e0 + t; e < e1; e += 1024) atomicAdd(&lh[dst[e] >> BKT_SHIFT], 1);
  __syncthreads();
  for (int k = t; k < NBKT; k += 1024) hist[k * NBLK + blk] = lh[k];
}

// ---------------- phase B1: per-bucket row scan (grid-parallel) ----------
__global__ __launch_bounds__(256) void row_scan_kernel(
    const int* __restrict__ hist, int* __restrict__ ebase, int* __restrict__ btot,
    int NBLK) {
  __shared__ int sh[256];
  const int k = blockIdx.x;
  const int t = threadIdx.x;
  int v = (t < NBLK) ? hist[(long)k * NBLK + t] : 0;
  sh[t] = v;
  __syncthreads();
  for (int s = 1; s < 256; s <<= 1) {
    int add = (t >= s) ? sh[t - s] : 0;
    __syncthreads();
    sh[t] += add;
    __syncthreads();
  }
  if (t < NBLK) ebase[(long)k * NBLK + t] = sh[t] - v;  // row-local exclusive
  if (t == 255) btot[k] = sh[255];
}

// ---------------- phase B2: scan bucket totals (single block, LDS-only) --
__global__ __launch_bounds__(1024) void bucket_scan_kernel(
    const int* __restrict__ btot, int* __restrict__ bbase, int E, int NBKT) {
  __shared__ int sh[1024];
  const int t = threadIdx.x;
  int v = (t < NBKT) ? btot[t] : 0;
  sh[t] = v;
  __syncthreads();
  for (int s = 1; s < 1024; s <<= 1) {
    int add = (t >= s) ? sh[t - s] : 0;
    __syncthreads();
    sh[t] += add;
    __syncthreads();
  }
  if (t < NBKT) bbase[t] = sh[t] - v;
  if (t == 0) bbase[NBKT] = E;
}

// ---------------- phase C: group edges by bucket (sequential runs) --------
__global__ __launch_bounds__(1024) void group_kernel(
    const int* __restrict__ src, const int* __restrict__ dst,
    const int* __restrict__ bbase, const int* __restrict__ ebase,
    unsigned int* __restrict__ grouped, int E, int NBKT, int NBLK) {
  __shared__ int lcur[1024];
  const int t = threadIdx.x;
  const int blk = blockIdx.x;
  for (int k = t; k < NBKT; k += 1024)
    lcur[k] = bbase[k] + ebase[(long)k * NBLK + blk];
  __syncthreads();
  const int e0 = blk * EPB;
  const int e1 = min(e0 + EPB, E);
  for (int e = e0 + t; e < e1; e += 1024) {
    int d = dst[e];
    int b = d >> BKT_SHIFT;
    int pos = atomicAdd(&lcur[b], 1);
    grouped[pos] = ((unsigned int)(d & (BKT_NODES - 1)) << 17) | (unsigned int)src[e];
  }
}

// ---------------- phase D (slim): per-bucket degree -> dis ----------------
__global__ __launch_bounds__(256) void bucket_deg_kernel(
    const unsigned int* __restrict__ grouped, const int* __restrict__ bbase,
    float* __restrict__ dis, int N) {
  __shared__ int lcnt[BKT_NODES];
  const int b = blockIdx.x;
  const int t = threadIdx.x;
  if (t < BKT_NODES) lcnt[t] = 0;
  const int base = bbase[b];
  const int m = bbase[b + 1] - base;
  __syncthreads();
  for (int i = t; i < m; i += 256) atomicAdd(&lcnt[grouped[base + i] >> 17], 1);
  __syncthreads();
  const int node0 = b << BKT_SHIFT;
  if (t < BKT_NODES && node0 + t < N)
    dis[node0 + t] = 1.0f / sqrtf((float)(lcnt[t] + 1));  // +1 self loop
}

// ------- MFMA GEMM: C[N,64] = fp16( (H[N,K] @ W[K,64]) * dis[row] ) -----
// 64 rows/block, 256 thr = 4 waves; wave w owns rows 16w..16w+15.
// Whole K staged: Hs[64][K] fp16, Ws[64][K] fp16 (= W^T), both XOR-swizzled.

template <int K, typename Tin>
__global__ __launch_bounds__(256) void gemm_mfma_kernel(
    const Tin* __restrict__ H, const float* __restrict__ W,
    const float* __restrict__ dis, __half* __restrict__ C, int N) {
  __shared__ __align__(16) __half Hs[64 * K];
  __shared__ __align__(16) __half Ws[64 * K];
  const int t = threadIdx.x;
  const int rowBase = blockIdx.x * 64;

  // ---- stage H (cast to fp16, swizzled) ----
  if constexpr (sizeof(Tin) == 4) {
    const int NF4 = 64 * K / 4;
#pragma unroll
    for (int i = 0; i < NF4 / 256; ++i) {
      int f = t + i * 256;
      int row = f / (K / 4);
      int c4 = f % (K / 4);
      int gr = rowBase + row;
      float4 v = make_float4(0.f, 0.f, 0.f, 0.f);
      if (gr < N) v = *reinterpret_cast<const float4*>(H + (long)gr * K + c4 * 4);
      union { uint2 u; __half2 h[2]; } pk;
      pk.h[0] = __floats2half2_rn(v.x, v.y);
      pk.h[1] = __floats2half2_rn(v.z, v.w);
      int byte = (row * K + c4 * 4) * 2;
      byte ^= (row & 7) << 4;
      *reinterpret_cast<uint2*>(reinterpret_cast<char*>(Hs) + byte) = pk.u;
    }
  } else {
    const int NC = 64 * K / 8;
#pragma unroll
    for (int i = 0; i < NC / 256; ++i) {
      int f = t + i * 256;
      int row = f / (K / 8);
      int c8 = f % (K / 8);
      int gr = rowBase + row;
      uint4 v = make_uint4(0u, 0u, 0u, 0u);
      if (gr < N) v = *reinterpret_cast<const uint4*>(H + (long)gr * K + c8 * 8);
      int byte = (row * K + c8 * 8) * 2;
      byte ^= (row & 7) << 4;
      *reinterpret_cast<uint4*>(reinterpret_cast<char*>(Hs) + byte) = v;
    }
  }

  // ---- stage W^T (transpose via half2 k-pairs, swizzled) ----
  {
    const int NU = (K / 2) * 16;  // (k-pair, col-quad) units
#pragma unroll
    for (int i = 0; i < NU / 256; ++i) {
      int u = t + i * 256;
      int kp = u >> 4;
      int cq = u & 15;
      const float4 w0 = *reinterpret_cast<const float4*>(W + (long)(2 * kp) * 64 + cq * 4);
      const float4 w1 = *reinterpret_cast<const float4*>(W + (long)(2 * kp + 1) * 64 + cq * 4);
#pragma unroll
      for (int j = 0; j < 4; ++j) {
        int c = cq * 4 + j;
        __half2 p = __floats2half2_rn((&w0.x)[j], (&w1.x)[j]);
        int byte = (c * K + 2 * kp) * 2;
        byte ^= (c & 7) << 4;
        *reinterpret_cast<__half2*>(reinterpret_cast<char*>(Ws) + byte) = p;
      }
    }
  }
  __syncthreads();

  // ---- MFMA: wave computes 16 rows x 64 cols ----
  const int w = t >> 6;
  const int l = t & 63;
  const int r = l & 15;
  const int g = l >> 4;
  const int rowL = 16 * w + r;
  f32x4 acc[4] = {{0.f, 0.f, 0.f, 0.f}, {0.f, 0.f, 0.f, 0.f},
                  {0.f, 0.f, 0.f, 0.f}, {0.f, 0.f, 0.f, 0.f}};
#pragma unroll
  for (int s = 0; s < K / 32; ++s) {
    int abyte = (rowL * K + s * 32 + g * 8) * 2;
    abyte ^= (rowL & 7) << 4;
    f16x8 afrag = *reinterpret_cast<const f16x8*>(reinterpret_cast<const char*>(Hs) + abyte);
#pragma unroll
    for (int n = 0; n < 4; ++n) {
      int col = n * 16 + r;
      int bbyte = (col * K + s * 32 + g * 8) * 2;
      bbyte ^= (col & 7) << 4;
      f16x8 bfrag = *reinterpret_cast<const f16x8*>(reinterpret_cast<const char*>(Ws) + bbyte);
      acc[n] = __builtin_amdgcn_mfma_f32_16x16x32_f16(afrag, bfrag, acc[n], 0, 0, 0);
    }
  }

  // ---- epilogue: scale by dis[row], round to fp16 ----
  const int outRow0 = rowBase + 16 * w + 4 * g;
#pragma unroll
  for (int j = 0; j < 4; ++j) {
    int row = outRow0 + j;
    if (row < N) {
      float dv = dis[row];
#pragma unroll
      for (int n = 0; n < 4; ++n) {
        C[(long)row * 64 + n * 16 + r] = __float2half(acc[n][j] * dv);
      }
    }
  }
}

// -------- aggregation: edge-parallel per-bucket LDS-atomic ---------------
// Block = one 128-node bucket, 512 thr = 8 waves. acc[128][65] fp32 in LDS.
// Per wave-instr: 4 edges x 16 lanes x uint2 (coalesced 128B row gathers),
// native ds_add_f32 via unsafeAtomicAdd (NOT atomicAdd: that CAS-loops on
// fp32 LDS without -munsafe-fp-atomics -- R14 evidence, 682us @ VALU 1.65%).
// Epilogue: out = fp16(relu(dis*(acc+self)+bias)).

__device__ __forceinline__ float4 h4_to_f4(uint2 u) {
  const __half2 lo = *reinterpret_cast<const __half2*>(&u.x);
  const __half2 hi = *reinterpret_cast<const __half2*>(&u.y);
  const float2 flo = __half22float2(lo);
  const float2 fhi = __half22float2(hi);
  return make_float4(flo.x, flo.y, fhi.x, fhi.y);
}

__global__ __launch_bounds__(512) void aggregate_bucket_kernel(
    const __half* __restrict__ Ts, const unsigned int* __restrict__ grouped,
    const int* __restrict__ bbase, const float* __restrict__ dis,
    const float* __restrict__ bias, __half* __restrict__ O, int N) {
  __shared__ float acc[BKT_NODES * ACC_STRIDE];  // 33.3 KB
  const int b = blockIdx.x;
  const int t = threadIdx.x;
  for (int i = t; i < BKT_NODES * ACC_STRIDE; i += 512) acc[i] = 0.f;
  const int base = bbase[b];
  const int m = bbase[b + 1] - base;
  __syncthreads();

  const int w = t >> 6;          // wave id 0..7
  const int l = t & 63;
  const int q = l >> 4;          // edge-in-quad 0..3
  const int c = l & 15;          // row quarter (uint2) 0..15
  const uint2* Tv = (const uint2*)Ts;

  const int Q = (m + 3) >> 2;    // quads
#pragma unroll 2
  for (int qi = w; qi < Q; qi += 8) {
    const int e = qi * 4 + q;
    if (e < m) {
      unsigned int g = grouped[base + e];
      int srcn = (int)(g & 0x1FFFFu);
      int dl = (int)(g >> 17);
      uint2 v = Tv[(long)srcn * 16 + c];
      float4 f = h4_to_f4(v);
      float* ap = &acc[dl * ACC_STRIDE + c * 4];
      unsafeAtomicAdd(ap + 0, f.x);
      unsafeAtomicAdd(ap + 1, f.y);
      unsafeAtomicAdd(ap + 2, f.z);
      unsafeAtomicAdd(ap + 3, f.w);
    }
  }
  __syncthreads();

  // epilogue: thread -> row t>>2, 16 cols each (4 uint2)
  const int node0 = b << BKT_SHIFT;
  const int r = t >> 2;
  const int row = node0 + r;
  if (row < N) {
    const int u0 = (t & 3) * 4;  // uint2 index base within row
    const float dd = dis[row];
    uint2 ov[4];
#pragma unroll
    for (int u = 0; u < 4; ++u) {
      uint2 sv = Tv[(long)row * 16 + u0 + u];           // self loop (pre-scaled)
      float4 sf = h4_to_f4(sv);
      const float* ap = &acc[r * ACC_STRIDE + (u0 + u) * 4];
      float4 b4 = ((const float4*)bias)[u0 + u];
      union { uint2 uu; __half2 h[2]; } pk;
      pk.h[0] = __floats2half2_rn(fmaxf((ap[0] + sf.x) * dd + b4.x, 0.f),
                                  fmaxf((ap[1] + sf.y) * dd + b4.y, 0.f));
      pk.h[1] = __floats2half2_rn(fmaxf((ap[2] + sf.z) * dd + b4.z, 0.f),
                                  fmaxf((ap[3] + sf.w) * dd + b4.w, 0.f));
      ov[u] = pk.uu;
    }
#pragma unroll
    for (int u = 0; u < 4; ++u)
      ((uint2*)O)[(long)row * 16 + u0 + u] = ov[u];
  }
}

// ---------------- pooling ----------------

__global__ void logits_kernel(const float* __restrict__ clo, const float* __restrict__ Wc,
                              const float* __restrict__ bc, float* __restrict__ lb, int N) {
  int i = blockIdx.x * blockDim.x + threadIdx.x;
  if (i >= N) return;
  float s = bc[0];
#pragma unroll
  for (int k = 0; k < 8; ++k) s += clo[(long)i * 8 + k] * Wc[k];
  lb[i] = s;
}

__global__ __launch_bounds__(256) void pool_kernel(
    const __half* __restrict__ h3, const float* __restrict__ lb,
    const int* __restrict__ batch, const float* __restrict__ Wa1,
    const float* __restrict__ ba1, const float* __restrict__ Wa2,
    const float* __restrict__ ba2, float* __restrict__ out, int N) {
  __shared__ int sLo, sHi;
  __shared__ float red[256];
  __shared__ float Vs[4][64];
  __shared__ float sse[4];
  __shared__ float gv[64];
  __shared__ float am[16];
  const int g = blockIdx.x;
  const int t = threadIdx.x;
  if (t == 0) {
    int lo = 0, hi = N;
    while (lo < hi) { int mid = (lo + hi) >> 1; if (batch[mid] < g) lo = mid + 1; else hi = mid; }
    sLo = lo;
    lo = 0; hi = N;
    while (lo < hi) { int mid = (lo + hi) >> 1; if (batch[mid] < g + 1) lo = mid + 1; else hi = mid; }
    sHi = lo;
  }
  __syncthreads();
  const int lo = sLo, hi = sHi;

  float lm = -1e30f;
  for (int i = lo + t; i < hi; i += 256) lm = fmaxf(lm, lb[i]);
  red[t] = lm;
  __syncthreads();
  for (int s = 128; s > 0; s >>= 1) {
    if (t < s) red[t] = fmaxf(red[t], red[t + s]);
    __syncthreads();
  }
  const float m = red[0];

  const int f = t & 63, sub = t >> 6;
  float vacc = 0.f, seacc = 0.f;
  for (int i = lo + sub; i < hi; i += 4) {
    float e = expf(lb[i] - m);
    seacc += e;
    vacc += e * __half2float(h3[(long)i * 64 + f]);
  }
  Vs[sub][f] = vacc;
  if (f == 0) sse[sub] = seacc;
  __syncthreads();
  if (t < 64) {
    float se = sse[0] + sse[1] + sse[2] + sse[3];
    float v = Vs[0][f] + Vs[1][f] + Vs[2][f] + Vs[3][f];
    gv[f] = (se > 0.f) ? v / se : 0.f;
  }
  __syncthreads();
  if (t < 16) {
    float a = ba1[t];
#pragma unroll
    for (int k2 = 0; k2 < 64; ++k2) a += gv[k2] * Wa1[k2 * 16 + t];
    am[t] = a > 0.f ? a : 0.f;
  }
  __syncthreads();
  if (t == 0) {
    float o = ba2[0];
#pragma unroll
    for (int j = 0; j < 16; ++j) o += am[j] * Wa2[j];
    out[g] = o;
  }
}

// ---------------- launcher ----------------

extern "C" void kernel_launch(void* const* d_in, const int* in_sizes, int n_in,
                              void* d_out, int out_size, void* d_ws, size_t ws_size,
                              hipStream_t stream) {
  const float* x   = (const float*)d_in[0];
  const float* clo = (const float*)d_in[1];
  const float* W1  = (const float*)d_in[2];
  const float* b1  = (const float*)d_in[3];
  const float* W2  = (const float*)d_in[4];
  const float* b2  = (const float*)d_in[5];
  const float* W3  = (const float*)d_in[6];
  const float* b3  = (const float*)d_in[7];
  const float* Wc  = (const float*)d_in[8];
  const float* bc  = (const float*)d_in[9];
  const float* Wa1 = (const float*)d_in[10];
  const float* ba1 = (const float*)d_in[11];
  const float* Wa2 = (const float*)d_in[12];
  const float* ba2 = (const float*)d_in[13];
  const int* edge  = (const int*)d_in[14];
  const int* batch = (const int*)d_in[15];
  float* out = (float*)d_out;

  const int N = in_sizes[15];        // 100000
  const int E = in_sizes[14] / 2;    // 1600000
  const int G = out_size;            // 256
  const int NBKT = (N + BKT_NODES - 1) >> BKT_SHIFT;  // 782 (<=1024)
  const int NBLK = (E + EPB - 1) / EPB;               // 196 (<=256)

  const int* src = edge;
  const int* dst = edge + E;

  char* p = (char*)d_ws;
  auto alloc = [&](size_t bytes) -> char* {
    char* r = p;
    p += (bytes + 255) & ~(size_t)255;
    return r;
  };
  __half* tsbuf         = (__half*)alloc((size_t)N * 64 * sizeof(__half));
  __half* bufH          = (__half*)alloc((size_t)N * 64 * sizeof(__half));
  unsigned int* grouped = (unsigned int*)alloc((size_t)E * sizeof(unsigned int));
  int*   hist           = (int*)  alloc((size_t)NBKT * NBLK * sizeof(int));
  int*   ebase          = (int*)  alloc((size_t)NBKT * NBLK * sizeof(int));
  int*   btot           = (int*)  alloc((size_t)NBKT * sizeof(int));
  int*   bbase          = (int*)  alloc((size_t)(NBKT + 1) * sizeof(int));
  float* dis            = (float*)alloc((size_t)N * sizeof(float));
  float* lb             = (float*)alloc((size_t)N * sizeof(float));
  (void)ws_size; (void)n_in;

  block_hist_kernel<<<NBLK, 1024, 0, stream>>>(dst, hist, E, NBKT, NBLK);
  row_scan_kernel<<<NBKT, 256, 0, stream>>>(hist, ebase, btot, NBLK);
  bucket_scan_kernel<<<1, 1024, 0, stream>>>(btot, bbase, E, NBKT);
  group_kernel<<<NBLK, 1024, 0, stream>>>(src, dst, bbase, ebase, grouped, E, NBKT, NBLK);
  bucket_deg_kernel<<<NBKT, 256, 0, stream>>>(grouped, bbase, dis, N);

  const int gN = (N + 255) / 256;
  const int gGemm = (N + 63) / 64;

  gemm_mfma_kernel<128, float><<<gGemm, 256, 0, stream>>>(x, W1, dis, tsbuf, N);
  aggregate_bucket_kernel<<<NBKT, 512, 0, stream>>>(tsbuf, grouped, bbase, dis, b1, bufH, N);
  gemm_mfma_kernel<64, __half><<<gGemm, 256, 0, stream>>>(bufH, W2, dis, tsbuf, N);
  aggregate_bucket_kernel<<<NBKT, 512, 0, stream>>>(tsbuf, grouped, bbase, dis, b2, bufH, N);
  gemm_mfma_kernel<64, __half><<<gGemm, 256, 0, stream>>>(bufH, W3, dis, tsbuf, N);
  aggregate_bucket_kernel<<<NBKT, 512, 0, stream>>>(tsbuf, grouped, bbase, dis, b3, bufH, N);

  logits_kernel<<<gN, 256, 0, stream>>>(clo, Wc, bc, lb, N);
  pool_kernel<<<G, 256, 0, stream>>>(bufH, lb, batch, Wa1, ba1, Wa2, ba2, out, N);
}

// Round 6
// 357.909 us; speedup vs baseline: 6.3105x; 6.3105x over previous
//
#include <hip/hip_runtime.h>
#include <hip/hip_fp16.h>
#include <math.h>

// R7: contention-free radix CSR build. R12: fp16 gather table. R13: MFMA
// GEMM (16x16x32 f16) -> 352.0us. R14/R15: edge-parallel LDS-RMW aggregate
// FAILED (682us, VALU 1.65% spin; atomicAdd and unsafeAtomicAdd identical
// codegen -- LDS fp32 RMW not viable from HIP here). REVERTED to R13 CSR.
// R16 (this round): aggregate 16-lanes-per-node, 4 nodes/wave. R13 evidence:
// latency/issue-bound (VALU 52%, HBM 27%); per-node structure overhead
// (64-wide idx load 75% idle, 4-acc merge, 12-shfl reduce, 16/64-lane store)
// all eliminated; same gather width (4 random 128B rows per instr).

#define BKT_SHIFT 7
#define BKT_NODES 128
#define BKT_CAP 4096   // LDS staging cap; overflow -> direct-write fallback
#define EPB 8192       // edges per block in hist/group passes

typedef _Float16 f16x8 __attribute__((ext_vector_type(8)));
typedef float f32x4 __attribute__((ext_vector_type(4)));

// ---------------- phase A: per-(bucket,block) histogram ----------------
__global__ __launch_bounds__(1024) void block_hist_kernel(
    const int* __restrict__ dst, int* __restrict__ hist, int E, int NBKT, int NBLK) {
  __shared__ int lh[1024];  // >= NBKT
  const int t = threadIdx.x;
  const int blk = blockIdx.x;
  for (int k = t; k < NBKT; k += 1024) lh[k] = 0;
  __syncthreads();
  const int e0 = blk * EPB;
  const int e1 = min(e0 + EPB, E);
  for (int e = e0 + t; e < e1; e += 1024) atomicAdd(&lh[dst[e] >> BKT_SHIFT], 1);
  __syncthreads();
  for (int k = t; k < NBKT; k += 1024) hist[k * NBLK + blk] = lh[k];
}

// ---------------- phase B1: per-bucket row scan (grid-parallel) ----------
__global__ __launch_bounds__(256) void row_scan_kernel(
    const int* __restrict__ hist, int* __restrict__ ebase, int* __restrict__ btot,
    int NBLK) {
  __shared__ int sh[256];
  const int k = blockIdx.x;
  const int t = threadIdx.x;
  int v = (t < NBLK) ? hist[(long)k * NBLK + t] : 0;
  sh[t] = v;
  __syncthreads();
  for (int s = 1; s < 256; s <<= 1) {
    int add = (t >= s) ? sh[t - s] : 0;
    __syncthreads();
    sh[t] += add;
    __syncthreads();
  }
  if (t < NBLK) ebase[(long)k * NBLK + t] = sh[t] - v;  // row-local exclusive
  if (t == 255) btot[k] = sh[255];
}

// ---------------- phase B2: scan bucket totals (single block, LDS-only) --
__global__ __launch_bounds__(1024) void bucket_scan_kernel(
    const int* __restrict__ btot, int* __restrict__ bbase, int E, int NBKT) {
  __shared__ int sh[1024];
  const int t = threadIdx.x;
  int v = (t < NBKT) ? btot[t] : 0;
  sh[t] = v;
  __syncthreads();
  for (int s = 1; s < 1024; s <<= 1) {
    int add = (t >= s) ? sh[t - s] : 0;
    __syncthreads();
    sh[t] += add;
    __syncthreads();
  }
  if (t < NBKT) bbase[t] = sh[t] - v;
  if (t == 0) bbase[NBKT] = E;
}

// ---------------- phase C: group edges by bucket (sequential runs) --------
__global__ __launch_bounds__(1024) void group_kernel(
    const int* __restrict__ src, const int* __restrict__ dst,
    const int* __restrict__ bbase, const int* __restrict__ ebase,
    unsigned int* __restrict__ grouped, int E, int NBKT, int NBLK) {
  __shared__ int lcur[1024];
  const int t = threadIdx.x;
  const int blk = blockIdx.x;
  for (int k = t; k < NBKT; k += 1024)
    lcur[k] = bbase[k] + ebase[(long)k * NBLK + blk];
  __syncthreads();
  const int e0 = blk * EPB;
  const int e1 = min(e0 + EPB, E);
  for (int e = e0 + t; e < e1; e += 1024) {
    int d = dst[e];
    int b = d >> BKT_SHIFT;
    int pos = atomicAdd(&lcur[b], 1);
    grouped[pos] = ((unsigned int)(d & (BKT_NODES - 1)) << 17) | (unsigned int)src[e];
  }
}

// ---------------- phase D: per-bucket CSR finalize + ends + dis ----------
__global__ __launch_bounds__(256) void bucket_build_kernel(
    const unsigned int* __restrict__ grouped, const int* __restrict__ bbase,
    int* __restrict__ csr_src, int* __restrict__ ends, float* __restrict__ dis, int N) {
  __shared__ int lcnt[BKT_NODES];
  __shared__ int lsum[BKT_NODES];
  __shared__ int lcur[BKT_NODES];
  __shared__ int stage[BKT_CAP];
  const int b = blockIdx.x;
  const int t = threadIdx.x;
  const int node0 = b << BKT_SHIFT;
  const int nn = min(BKT_NODES, N - node0);
  const int base = bbase[b];
  const int m = bbase[b + 1] - base;

  if (t < BKT_NODES) lcnt[t] = 0;
  __syncthreads();
  for (int i = t; i < m; i += 256) atomicAdd(&lcnt[grouped[base + i] >> 17], 1);
  __syncthreads();
  if (t < BKT_NODES) lsum[t] = lcnt[t];
  __syncthreads();
  for (int s = 1; s < BKT_NODES; s <<= 1) {
    int add = 0;
    if (t < BKT_NODES && t >= s) add = lsum[t - s];
    __syncthreads();
    if (t < BKT_NODES) lsum[t] += add;
    __syncthreads();
  }
  if (t < nn) {
    ends[node0 + t] = base + lsum[t];                      // global inclusive end
    dis[node0 + t] = 1.0f / sqrtf((float)(lcnt[t] + 1));   // +1 self loop
    lcur[t] = lsum[t] - lcnt[t];                           // local exclusive cursor
  }
  __syncthreads();
  if (m <= BKT_CAP) {
    for (int i = t; i < m; i += 256) {
      unsigned int v = grouped[base + i];
      int p = atomicAdd(&lcur[v >> 17], 1);
      stage[p] = (int)(v & 0x1FFFFu);
    }
    __syncthreads();
    for (int i = t; i < m; i += 256) csr_src[base + i] = stage[i];
  } else {  // statistically never; correctness fallback
    for (int i = t; i < m; i += 256) {
      unsigned int v = grouped[base + i];
      int p = atomicAdd(&lcur[v >> 17], 1);
      csr_src[base + p] = (int)(v & 0x1FFFFu);
    }
  }
}

// ------- MFMA GEMM: C[N,64] = fp16( (H[N,K] @ W[K,64]) * dis[row] ) -----
// 64 rows/block, 256 thr = 4 waves; wave w owns rows 16w..16w+15.
// Whole K staged: Hs[64][K] fp16, Ws[64][K] fp16 (= W^T), both XOR-swizzled.

template <int K, typename Tin>
__global__ __launch_bounds__(256) void gemm_mfma_kernel(
    const Tin* __restrict__ H, const float* __restrict__ W,
    const float* __restrict__ dis, __half* __restrict__ C, int N) {
  __shared__ __align__(16) __half Hs[64 * K];
  __shared__ __align__(16) __half Ws[64 * K];
  const int t = threadIdx.x;
  const int rowBase = blockIdx.x * 64;

  // ---- stage H (cast to fp16, swizzled) ----
  if constexpr (sizeof(Tin) == 4) {
    const int NF4 = 64 * K / 4;
#pragma unroll
    for (int i = 0; i < NF4 / 256; ++i) {
      int f = t + i * 256;
      int row = f / (K / 4);
      int c4 = f % (K / 4);
      int gr = rowBase + row;
      float4 v = make_float4(0.f, 0.f, 0.f, 0.f);
      if (gr < N) v = *reinterpret_cast<const float4*>(H + (long)gr * K + c4 * 4);
      union { uint2 u; __half2 h[2]; } pk;
      pk.h[0] = __floats2half2_rn(v.x, v.y);
      pk.h[1] = __floats2half2_rn(v.z, v.w);
      int byte = (row * K + c4 * 4) * 2;
      byte ^= (row & 7) << 4;
      *reinterpret_cast<uint2*>(reinterpret_cast<char*>(Hs) + byte) = pk.u;
    }
  } else {
    const int NC = 64 * K / 8;
#pragma unroll
    for (int i = 0; i < NC / 256; ++i) {
      int f = t + i * 256;
      int row = f / (K / 8);
      int c8 = f % (K / 8);
      int gr = rowBase + row;
      uint4 v = make_uint4(0u, 0u, 0u, 0u);
      if (gr < N) v = *reinterpret_cast<const uint4*>(H + (long)gr * K + c8 * 8);
      int byte = (row * K + c8 * 8) * 2;
      byte ^= (row & 7) << 4;
      *reinterpret_cast<uint4*>(reinterpret_cast<char*>(Hs) + byte) = v;
    }
  }

  // ---- stage W^T (transpose via half2 k-pairs, swizzled) ----
  {
    const int NU = (K / 2) * 16;  // (k-pair, col-quad) units
#pragma unroll
    for (int i = 0; i < NU / 256; ++i) {
      int u = t + i * 256;
      int kp = u >> 4;
      int cq = u & 15;
      const float4 w0 = *reinterpret_cast<const float4*>(W + (long)(2 * kp) * 64 + cq * 4);
      const float4 w1 = *reinterpret_cast<const float4*>(W + (long)(2 * kp + 1) * 64 + cq * 4);
#pragma unroll
      for (int j = 0; j < 4; ++j) {
        int c = cq * 4 + j;
        __half2 p = __floats2half2_rn((&w0.x)[j], (&w1.x)[j]);
        int byte = (c * K + 2 * kp) * 2;
        byte ^= (c & 7) << 4;
        *reinterpret_cast<__half2*>(reinterpret_cast<char*>(Ws) + byte) = p;
      }
    }
  }
  __syncthreads();

  // ---- MFMA: wave computes 16 rows x 64 cols ----
  const int w = t >> 6;
  const int l = t & 63;
  const int r = l & 15;
  const int g = l >> 4;
  const int rowL = 16 * w + r;
  f32x4 acc[4] = {{0.f, 0.f, 0.f, 0.f}, {0.f, 0.f, 0.f, 0.f},
                  {0.f, 0.f, 0.f, 0.f}, {0.f, 0.f, 0.f, 0.f}};
#pragma unroll
  for (int s = 0; s < K / 32; ++s) {
    int abyte = (rowL * K + s * 32 + g * 8) * 2;
    abyte ^= (rowL & 7) << 4;
    f16x8 afrag = *reinterpret_cast<const f16x8*>(reinterpret_cast<const char*>(Hs) + abyte);
#pragma unroll
    for (int n = 0; n < 4; ++n) {
      int col = n * 16 + r;
      int bbyte = (col * K + s * 32 + g * 8) * 2;
      bbyte ^= (col & 7) << 4;
      f16x8 bfrag = *reinterpret_cast<const f16x8*>(reinterpret_cast<const char*>(Ws) + bbyte);
      acc[n] = __builtin_amdgcn_mfma_f32_16x16x32_f16(afrag, bfrag, acc[n], 0, 0, 0);
    }
  }

  // ---- epilogue: scale by dis[row], round to fp16 ----
  const int outRow0 = rowBase + 16 * w + 4 * g;
#pragma unroll
  for (int j = 0; j < 4; ++j) {
    int row = outRow0 + j;
    if (row < N) {
      float dv = dis[row];
#pragma unroll
      for (int n = 0; n < 4; ++n) {
        C[(long)row * 64 + n * 16 + r] = __float2half(acc[n][j] * dv);
      }
    }
  }
}

// -------- aggregation: CSR, 16 lanes/node, 4 nodes/wave ------------------
// Lane (g,c) owns cols 4c..4c+3 of node d=wid*4+g. Per-lane accumulation:
// no cross-lane reduce, no acc merge, no idle lanes. Gather width unchanged
// (one instr = 4 random 128B rows). Inner 16-trip loop is wave-uniform so
// intra-group shfl stays convergent; adds guarded per group.

__device__ __forceinline__ float4 h4_to_f4(uint2 u) {
  const __half2 lo = *reinterpret_cast<const __half2*>(&u.x);
  const __half2 hi = *reinterpret_cast<const __half2*>(&u.y);
  const float2 flo = __half22float2(lo);
  const float2 fhi = __half22float2(hi);
  return make_float4(flo.x, flo.y, fhi.x, fhi.y);
}

__global__ __launch_bounds__(256) void aggregate_kernel(
    const __half* __restrict__ Ts, const int* __restrict__ csr_src,
    const int* __restrict__ ends, const float* __restrict__ dis,
    const float* __restrict__ bias, __half* __restrict__ O, int N) {
  const int wid = (blockIdx.x * 256 + threadIdx.x) >> 6;
  const int l = threadIdx.x & 63;
  const int g = l >> 4;         // node within wave quad
  const int c = l & 15;         // uint2 column of the 128B row
  const int d = wid * 4 + g;
  if (d >= N) return;           // whole 16-lane group exits together
  const int beg = (d == 0) ? 0 : ends[d - 1];
  const int m = ends[d] - beg;  // group-uniform
  const uint2* Tv = (const uint2*)Ts;

  // self loop (pre-scaled by dis[d])
  float4 a = h4_to_f4(Tv[(long)d * 16 + c]);

  // wave-uniform outer trip count so shfl stays convergent
  int mmax = m;
  mmax = max(mmax, __shfl_xor(mmax, 16, 64));
  mmax = max(mmax, __shfl_xor(mmax, 32, 64));

  const int gbase = l & 48;     // first lane of this group
  for (int base = 0; base < mmax; base += 16) {
    const int take = m - base;  // group-uniform; may be <=0 or >16
    int idx = (c < take) ? csr_src[beg + base + c] : 0;
#pragma unroll 4
    for (int j = 0; j < 16; ++j) {
      int s = __shfl(idx, gbase + j, 64);
      if (j < take) {
        float4 f = h4_to_f4(Tv[(long)s * 16 + c]);
        a.x += f.x; a.y += f.y; a.z += f.z; a.w += f.w;
      }
    }
  }

  const float dd = dis[d];
  const float4 b4 = ((const float4*)bias)[c];
  union { uint2 uu; __half2 h[2]; } pk;
  pk.h[0] = __floats2half2_rn(fmaxf(a.x * dd + b4.x, 0.f),
                              fmaxf(a.y * dd + b4.y, 0.f));
  pk.h[1] = __floats2half2_rn(fmaxf(a.z * dd + b4.z, 0.f),
                              fmaxf(a.w * dd + b4.w, 0.f));
  ((uint2*)O)[(long)d * 16 + c] = pk.uu;
}

// ---------------- pooling ----------------

__global__ void logits_kernel(const float* __restrict__ clo, const float* __restrict__ Wc,
                              const float* __restrict__ bc, float* __restrict__ lb, int N) {
  int i = blockIdx.x * blockDim.x + threadIdx.x;
  if (i >= N) return;
  float s = bc[0];
#pragma unroll
  for (int k = 0; k < 8; ++k) s += clo[(long)i * 8 + k] * Wc[k];
  lb[i] = s;
}

__global__ __launch_bounds__(256) void pool_kernel(
    const __half* __restrict__ h3, const float* __restrict__ lb,
    const int* __restrict__ batch, const float* __restrict__ Wa1,
    const float* __restrict__ ba1, const float* __restrict__ Wa2,
    const float* __restrict__ ba2, float* __restrict__ out, int N) {
  __shared__ int sLo, sHi;
  __shared__ float red[256];
  __shared__ float Vs[4][64];
  __shared__ float sse[4];
  __shared__ float gv[64];
  __shared__ float am[16];
  const int g = blockIdx.x;
  const int t = threadIdx.x;
  if (t == 0) {
    int lo = 0, hi = N;
    while (lo < hi) { int mid = (lo + hi) >> 1; if (batch[mid] < g) lo = mid + 1; else hi = mid; }
    sLo = lo;
    lo = 0; hi = N;
    while (lo < hi) { int mid = (lo + hi) >> 1; if (batch[mid] < g + 1) lo = mid + 1; else hi = mid; }
    sHi = lo;
  }
  __syncthreads();
  const int lo = sLo, hi = sHi;

  float lm = -1e30f;
  for (int i = lo + t; i < hi; i += 256) lm = fmaxf(lm, lb[i]);
  red[t] = lm;
  __syncthreads();
  for (int s = 128; s > 0; s >>= 1) {
    if (t < s) red[t] = fmaxf(red[t], red[t + s]);
    __syncthreads();
  }
  const float m = red[0];

  const int f = t & 63, sub = t >> 6;
  float vacc = 0.f, seacc = 0.f;
  for (int i = lo + sub; i < hi; i += 4) {
    float e = expf(lb[i] - m);
    seacc += e;
    vacc += e * __half2float(h3[(long)i * 64 + f]);
  }
  Vs[sub][f] = vacc;
  if (f == 0) sse[sub] = seacc;
  __syncthreads();
  if (t < 64) {
    float se = sse[0] + sse[1] + sse[2] + sse[3];
    float v = Vs[0][f] + Vs[1][f] + Vs[2][f] + Vs[3][f];
    gv[f] = (se > 0.f) ? v / se : 0.f;
  }
  __syncthreads();
  if (t < 16) {
    float a = ba1[t];
#pragma unroll
    for (int k2 = 0; k2 < 64; ++k2) a += gv[k2] * Wa1[k2 * 16 + t];
    am[t] = a > 0.f ? a : 0.f;
  }
  __syncthreads();
  if (t == 0) {
    float o = ba2[0];
#pragma unroll
    for (int j = 0; j < 16; ++j) o += am[j] * Wa2[j];
    out[g] = o;
  }
}

// ---------------- launcher ----------------

extern "C" void kernel_launch(void* const* d_in, const int* in_sizes, int n_in,
                              void* d_out, int out_size, void* d_ws, size_t ws_size,
                              hipStream_t stream) {
  const float* x   = (const float*)d_in[0];
  const float* clo = (const float*)d_in[1];
  const float* W1  = (const float*)d_in[2];
  const float* b1  = (const float*)d_in[3];
  const float* W2  = (const float*)d_in[4];
  const float* b2  = (const float*)d_in[5];
  const float* W3  = (const float*)d_in[6];
  const float* b3  = (const float*)d_in[7];
  const float* Wc  = (const float*)d_in[8];
  const float* bc  = (const float*)d_in[9];
  const float* Wa1 = (const float*)d_in[10];
  const float* ba1 = (const float*)d_in[11];
  const float* Wa2 = (const float*)d_in[12];
  const float* ba2 = (const float*)d_in[13];
  const int* edge  = (const int*)d_in[14];
  const int* batch = (const int*)d_in[15];
  float* out = (float*)d_out;

  const int N = in_sizes[15];        // 100000
  const int E = in_sizes[14] / 2;    // 1600000
  const int G = out_size;            // 256
  const int NBKT = (N + BKT_NODES - 1) >> BKT_SHIFT;  // 782 (<=1024)
  const int NBLK = (E + EPB - 1) / EPB;               // 196 (<=256)

  const int* src = edge;
  const int* dst = edge + E;

  char* p = (char*)d_ws;
  auto alloc = [&](size_t bytes) -> char* {
    char* r = p;
    p += (bytes + 255) & ~(size_t)255;
    return r;
  };
  __half* tsbuf         = (__half*)alloc((size_t)N * 64 * sizeof(__half));
  __half* bufH          = (__half*)alloc((size_t)N * 64 * sizeof(__half));
  int*   csr_src        = (int*)  alloc((size_t)E * sizeof(int));
  unsigned int* grouped = (unsigned int*)alloc((size_t)E * sizeof(unsigned int));
  int*   hist           = (int*)  alloc((size_t)NBKT * NBLK * sizeof(int));
  int*   ebase          = (int*)  alloc((size_t)NBKT * NBLK * sizeof(int));
  int*   btot           = (int*)  alloc((size_t)NBKT * sizeof(int));
  int*   bbase          = (int*)  alloc((size_t)(NBKT + 1) * sizeof(int));
  int*   ends           = (int*)  alloc((size_t)N * sizeof(int));
  float* dis            = (float*)alloc((size_t)N * sizeof(float));
  float* lb             = (float*)alloc((size_t)N * sizeof(float));
  (void)ws_size; (void)n_in;

  block_hist_kernel<<<NBLK, 1024, 0, stream>>>(dst, hist, E, NBKT, NBLK);
  row_scan_kernel<<<NBKT, 256, 0, stream>>>(hist, ebase, btot, NBLK);
  bucket_scan_kernel<<<1, 1024, 0, stream>>>(btot, bbase, E, NBKT);
  group_kernel<<<NBLK, 1024, 0, stream>>>(src, dst, bbase, ebase, grouped, E, NBKT, NBLK);
  bucket_build_kernel<<<NBKT, 256, 0, stream>>>(grouped, bbase, csr_src, ends, dis, N);

  const int gN = (N + 255) / 256;
  const int gGemm = (N + 63) / 64;
  const int gAgg  = (N + 15) / 16;   // 16 nodes per 256-thread block

  gemm_mfma_kernel<128, float><<<gGemm, 256, 0, stream>>>(x, W1, dis, tsbuf, N);
  aggregate_kernel<<<gAgg, 256, 0, stream>>>(tsbuf, csr_src, ends, dis, b1, bufH, N);
  gemm_mfma_kernel<64, __half><<<gGemm, 256, 0, stream>>>(bufH, W2, dis, tsbuf, N);
  aggregate_kernel<<<gAgg, 256, 0, stream>>>(tsbuf, csr_src, ends, dis, b2, bufH, N);
  gemm_mfma_kernel<64, __half><<<gGemm, 256, 0, stream>>>(bufH, W3, dis, tsbuf, N);
  aggregate_kernel<<<gAgg, 256, 0, stream>>>(tsbuf, csr_src, ends, dis, b3, bufH, N);

  logits_kernel<<<gN, 256, 0, stream>>>(clo, Wc, bc, lb, N);
  pool_kernel<<<G, 256, 0, stream>>>(bufH, lb, batch, Wa1, ba1, Wa2, ba2, out, N);
}

// Round 7
// 324.942 us; speedup vs baseline: 6.9507x; 1.1015x over previous
//
#include <hip/hip_runtime.h>
#include <hip/hip_fp16.h>
#include <math.h>

// R7: contention-free radix CSR build. R12: fp16 gather table. R13: MFMA
// GEMM (16x16x32 f16). R14/R15: LDS fp32 RMW aggregate FAILED (CAS spin).
// R16: 16-lanes/node aggregate -- VALU 52->21.7% but time UNCHANGED (45.8us)
// => gather-LATENCY-bound, not issue-bound (HBM 27%, ~4 loads in flight).
// R17 (this round): aggregate ILP restructure. Prefetch idx chunks 0+1,
// stage ALL 32 row-loads to regs before accumulating (pad lanes clamp to
// row d = L1-hot), dynamic tail only for degree>32. In-flight loads/wave
// ~4 -> ~32. Predict aggregate 45.8 -> ~30us.

#define BKT_SHIFT 7
#define BKT_NODES 128
#define BKT_CAP 4096   // LDS staging cap; overflow -> direct-write fallback
#define EPB 8192       // edges per block in hist/group passes

typedef _Float16 f16x8 __attribute__((ext_vector_type(8)));
typedef float f32x4 __attribute__((ext_vector_type(4)));

// ---------------- phase A: per-(bucket,block) histogram ----------------
__global__ __launch_bounds__(1024) void block_hist_kernel(
    const int* __restrict__ dst, int* __restrict__ hist, int E, int NBKT, int NBLK) {
  __shared__ int lh[1024];  // >= NBKT
  const int t = threadIdx.x;
  const int blk = blockIdx.x;
  for (int k = t; k < NBKT; k += 1024) lh[k] = 0;
  __syncthreads();
  const int e0 = blk * EPB;
  const int e1 = min(e0 + EPB, E);
  for (int e = e0 + t; e < e1; e += 1024) atomicAdd(&lh[dst[e] >> BKT_SHIFT], 1);
  __syncthreads();
  for (int k = t; k < NBKT; k += 1024) hist[k * NBLK + blk] = lh[k];
}

// ---------------- phase B1: per-bucket row scan (grid-parallel) ----------
__global__ __launch_bounds__(256) void row_scan_kernel(
    const int* __restrict__ hist, int* __restrict__ ebase, int* __restrict__ btot,
    int NBLK) {
  __shared__ int sh[256];
  const int k = blockIdx.x;
  const int t = threadIdx.x;
  int v = (t < NBLK) ? hist[(long)k * NBLK + t] : 0;
  sh[t] = v;
  __syncthreads();
  for (int s = 1; s < 256; s <<= 1) {
    int add = (t >= s) ? sh[t - s] : 0;
    __syncthreads();
    sh[t] += add;
    __syncthreads();
  }
  if (t < NBLK) ebase[(long)k * NBLK + t] = sh[t] - v;  // row-local exclusive
  if (t == 255) btot[k] = sh[255];
}

// ---------------- phase B2: scan bucket totals (single block, LDS-only) --
__global__ __launch_bounds__(1024) void bucket_scan_kernel(
    const int* __restrict__ btot, int* __restrict__ bbase, int E, int NBKT) {
  __shared__ int sh[1024];
  const int t = threadIdx.x;
  int v = (t < NBKT) ? btot[t] : 0;
  sh[t] = v;
  __syncthreads();
  for (int s = 1; s < 1024; s <<= 1) {
    int add = (t >= s) ? sh[t - s] : 0;
    __syncthreads();
    sh[t] += add;
    __syncthreads();
  }
  if (t < NBKT) bbase[t] = sh[t] - v;
  if (t == 0) bbase[NBKT] = E;
}

// ---------------- phase C: group edges by bucket (sequential runs) --------
__global__ __launch_bounds__(1024) void group_kernel(
    const int* __restrict__ src, const int* __restrict__ dst,
    const int* __restrict__ bbase, const int* __restrict__ ebase,
    unsigned int* __restrict__ grouped, int E, int NBKT, int NBLK) {
  __shared__ int lcur[1024];
  const int t = threadIdx.x;
  const int blk = blockIdx.x;
  for (int k = t; k < NBKT; k += 1024)
    lcur[k] = bbase[k] + ebase[(long)k * NBLK + blk];
  __syncthreads();
  const int e0 = blk * EPB;
  const int e1 = min(e0 + EPB, E);
  for (int e = e0 + t; e < e1; e += 1024) {
    int d = dst[e];
    int b = d >> BKT_SHIFT;
    int pos = atomicAdd(&lcur[b], 1);
    grouped[pos] = ((unsigned int)(d & (BKT_NODES - 1)) << 17) | (unsigned int)src[e];
  }
}

// ---------------- phase D: per-bucket CSR finalize + ends + dis ----------
__global__ __launch_bounds__(256) void bucket_build_kernel(
    const unsigned int* __restrict__ grouped, const int* __restrict__ bbase,
    int* __restrict__ csr_src, int* __restrict__ ends, float* __restrict__ dis, int N) {
  __shared__ int lcnt[BKT_NODES];
  __shared__ int lsum[BKT_NODES];
  __shared__ int lcur[BKT_NODES];
  __shared__ int stage[BKT_CAP];
  const int b = blockIdx.x;
  const int t = threadIdx.x;
  const int node0 = b << BKT_SHIFT;
  const int nn = min(BKT_NODES, N - node0);
  const int base = bbase[b];
  const int m = bbase[b + 1] - base;

  if (t < BKT_NODES) lcnt[t] = 0;
  __syncthreads();
  for (int i = t; i < m; i += 256) atomicAdd(&lcnt[grouped[base + i] >> 17], 1);
  __syncthreads();
  if (t < BKT_NODES) lsum[t] = lcnt[t];
  __syncthreads();
  for (int s = 1; s < BKT_NODES; s <<= 1) {
    int add = 0;
    if (t < BKT_NODES && t >= s) add = lsum[t - s];
    __syncthreads();
    if (t < BKT_NODES) lsum[t] += add;
    __syncthreads();
  }
  if (t < nn) {
    ends[node0 + t] = base + lsum[t];                      // global inclusive end
    dis[node0 + t] = 1.0f / sqrtf((float)(lcnt[t] + 1));   // +1 self loop
    lcur[t] = lsum[t] - lcnt[t];                           // local exclusive cursor
  }
  __syncthreads();
  if (m <= BKT_CAP) {
    for (int i = t; i < m; i += 256) {
      unsigned int v = grouped[base + i];
      int p = atomicAdd(&lcur[v >> 17], 1);
      stage[p] = (int)(v & 0x1FFFFu);
    }
    __syncthreads();
    for (int i = t; i < m; i += 256) csr_src[base + i] = stage[i];
  } else {  // statistically never; correctness fallback
    for (int i = t; i < m; i += 256) {
      unsigned int v = grouped[base + i];
      int p = atomicAdd(&lcur[v >> 17], 1);
      csr_src[base + p] = (int)(v & 0x1FFFFu);
    }
  }
}

// ------- MFMA GEMM: C[N,64] = fp16( (H[N,K] @ W[K,64]) * dis[row] ) -----
// 64 rows/block, 256 thr = 4 waves; wave w owns rows 16w..16w+15.
// Whole K staged: Hs[64][K] fp16, Ws[64][K] fp16 (= W^T), both XOR-swizzled.

template <int K, typename Tin>
__global__ __launch_bounds__(256) void gemm_mfma_kernel(
    const Tin* __restrict__ H, const float* __restrict__ W,
    const float* __restrict__ dis, __half* __restrict__ C, int N) {
  __shared__ __align__(16) __half Hs[64 * K];
  __shared__ __align__(16) __half Ws[64 * K];
  const int t = threadIdx.x;
  const int rowBase = blockIdx.x * 64;

  // ---- stage H (cast to fp16, swizzled) ----
  if constexpr (sizeof(Tin) == 4) {
    const int NF4 = 64 * K / 4;
#pragma unroll
    for (int i = 0; i < NF4 / 256; ++i) {
      int f = t + i * 256;
      int row = f / (K / 4);
      int c4 = f % (K / 4);
      int gr = rowBase + row;
      float4 v = make_float4(0.f, 0.f, 0.f, 0.f);
      if (gr < N) v = *reinterpret_cast<const float4*>(H + (long)gr * K + c4 * 4);
      union { uint2 u; __half2 h[2]; } pk;
      pk.h[0] = __floats2half2_rn(v.x, v.y);
      pk.h[1] = __floats2half2_rn(v.z, v.w);
      int byte = (row * K + c4 * 4) * 2;
      byte ^= (row & 7) << 4;
      *reinterpret_cast<uint2*>(reinterpret_cast<char*>(Hs) + byte) = pk.u;
    }
  } else {
    const int NC = 64 * K / 8;
#pragma unroll
    for (int i = 0; i < NC / 256; ++i) {
      int f = t + i * 256;
      int row = f / (K / 8);
      int c8 = f % (K / 8);
      int gr = rowBase + row;
      uint4 v = make_uint4(0u, 0u, 0u, 0u);
      if (gr < N) v = *reinterpret_cast<const uint4*>(H + (long)gr * K + c8 * 8);
      int byte = (row * K + c8 * 8) * 2;
      byte ^= (row & 7) << 4;
      *reinterpret_cast<uint4*>(reinterpret_cast<char*>(Hs) + byte) = v;
    }
  }

  // ---- stage W^T (transpose via half2 k-pairs, swizzled) ----
  {
    const int NU = (K / 2) * 16;  // (k-pair, col-quad) units
#pragma unroll
    for (int i = 0; i < NU / 256; ++i) {
      int u = t + i * 256;
      int kp = u >> 4;
      int cq = u & 15;
      const float4 w0 = *reinterpret_cast<const float4*>(W + (long)(2 * kp) * 64 + cq * 4);
      const float4 w1 = *reinterpret_cast<const float4*>(W + (long)(2 * kp + 1) * 64 + cq * 4);
#pragma unroll
      for (int j = 0; j < 4; ++j) {
        int c = cq * 4 + j;
        __half2 p = __floats2half2_rn((&w0.x)[j], (&w1.x)[j]);
        int byte = (c * K + 2 * kp) * 2;
        byte ^= (c & 7) << 4;
        *reinterpret_cast<__half2*>(reinterpret_cast<char*>(Ws) + byte) = p;
      }
    }
  }
  __syncthreads();

  // ---- MFMA: wave computes 16 rows x 64 cols ----
  const int w = t >> 6;
  const int l = t & 63;
  const int r = l & 15;
  const int g = l >> 4;
  const int rowL = 16 * w + r;
  f32x4 acc[4] = {{0.f, 0.f, 0.f, 0.f}, {0.f, 0.f, 0.f, 0.f},
                  {0.f, 0.f, 0.f, 0.f}, {0.f, 0.f, 0.f, 0.f}};
#pragma unroll
  for (int s = 0; s < K / 32; ++s) {
    int abyte = (rowL * K + s * 32 + g * 8) * 2;
    abyte ^= (rowL & 7) << 4;
    f16x8 afrag = *reinterpret_cast<const f16x8*>(reinterpret_cast<const char*>(Hs) + abyte);
#pragma unroll
    for (int n = 0; n < 4; ++n) {
      int col = n * 16 + r;
      int bbyte = (col * K + s * 32 + g * 8) * 2;
      bbyte ^= (col & 7) << 4;
      f16x8 bfrag = *reinterpret_cast<const f16x8*>(reinterpret_cast<const char*>(Ws) + bbyte);
      acc[n] = __builtin_amdgcn_mfma_f32_16x16x32_f16(afrag, bfrag, acc[n], 0, 0, 0);
    }
  }

  // ---- epilogue: scale by dis[row], round to fp16 ----
  const int outRow0 = rowBase + 16 * w + 4 * g;
#pragma unroll
  for (int j = 0; j < 4; ++j) {
    int row = outRow0 + j;
    if (row < N) {
      float dv = dis[row];
#pragma unroll
      for (int n = 0; n < 4; ++n) {
        C[(long)row * 64 + n * 16 + r] = __float2half(acc[n][j] * dv);
      }
    }
  }
}

// -------- aggregation: CSR, 16 lanes/node, 4 nodes/wave, deep ILP --------
// Lane (g,c) owns cols 4c..4c+3 of node d=wid*4+g. Chunks 0+1 (32 edges)
// fully staged: idx prefetched, 32 row-loads issued before ANY accumulate
// (pad lanes clamp to row d = L1-hot). Dynamic tail for degree>32 only.

__device__ __forceinline__ float4 h4_to_f4(uint2 u) {
  const __half2 lo = *reinterpret_cast<const __half2*>(&u.x);
  const __half2 hi = *reinterpret_cast<const __half2*>(&u.y);
  const float2 flo = __half22float2(lo);
  const float2 fhi = __half22float2(hi);
  return make_float4(flo.x, flo.y, fhi.x, fhi.y);
}

__global__ __launch_bounds__(256) void aggregate_kernel(
    const __half* __restrict__ Ts, const int* __restrict__ csr_src,
    const int* __restrict__ ends, const float* __restrict__ dis,
    const float* __restrict__ bias, __half* __restrict__ O, int N) {
  const int wid = (blockIdx.x * 256 + threadIdx.x) >> 6;
  const int l = threadIdx.x & 63;
  const int g = l >> 4;         // node within wave quad
  const int c = l & 15;         // uint2 column of the 128B row
  const int d0 = wid * 4 + g;
  const bool valid = d0 < N;
  const int d = valid ? d0 : (N - 1);   // safe row for pad lanes
  const int beg = valid ? ((d0 == 0) ? 0 : ends[d0 - 1]) : 0;
  const int m = valid ? (ends[d0] - beg) : 0;   // group-uniform per valid group
  const uint2* Tv = (const uint2*)Ts;

  // self loop (pre-scaled by dis[d])
  float4 a = h4_to_f4(Tv[(long)d * 16 + c]);

  // wave-uniform outer trip count so shfl stays convergent
  int mmax = m;
  mmax = max(mmax, __shfl_xor(mmax, 16, 64));
  mmax = max(mmax, __shfl_xor(mmax, 32, 64));

  const int gbase = l & 48;     // first lane of this group

  // ---- prefetch indices for chunks 0 and 1 ----
  int idx0 = (c < m) ? csr_src[beg + c] : 0;
  int idx1 = (16 + c < m) ? csr_src[beg + 16 + c] : 0;

  // ---- stage all 32 row loads before accumulating ----
  uint2 fr0[16], fr1[16];
  const bool has0 = (mmax > 0), has1 = (mmax > 16);
  if (has0) {
#pragma unroll
    for (int j = 0; j < 16; ++j) {
      int s = __shfl(idx0, gbase + j, 64);
      s = (j < m) ? s : d;              // pad -> own row (L1-hot)
      fr0[j] = Tv[(long)s * 16 + c];
    }
  }
  if (has1) {
#pragma unroll
    for (int j = 0; j < 16; ++j) {
      int s = __shfl(idx1, gbase + j, 64);
      s = (j + 16 < m) ? s : d;
      fr1[j] = Tv[(long)s * 16 + c];
    }
  }
  if (has0) {
#pragma unroll
    for (int j = 0; j < 16; ++j) {
      if (j < m) {
        float4 f = h4_to_f4(fr0[j]);
        a.x += f.x; a.y += f.y; a.z += f.z; a.w += f.w;
      }
    }
  }
  if (has1) {
#pragma unroll
    for (int j = 0; j < 16; ++j) {
      if (j + 16 < m) {
        float4 f = h4_to_f4(fr1[j]);
        a.x += f.x; a.y += f.y; a.z += f.z; a.w += f.w;
      }
    }
  }

  // ---- dynamic tail (degree > 32; Poisson(16) => rare) ----
  for (int base = 32; base < mmax; base += 16) {
    const int take = m - base;
    int idx = (base + c < m) ? csr_src[beg + base + c] : 0;
    uint2 fr[16];
#pragma unroll
    for (int j = 0; j < 16; ++j) {
      int s = __shfl(idx, gbase + j, 64);
      s = (j < take) ? s : d;
      fr[j] = Tv[(long)s * 16 + c];
    }
#pragma unroll
    for (int j = 0; j < 16; ++j) {
      if (j < take) {
        float4 f = h4_to_f4(fr[j]);
        a.x += f.x; a.y += f.y; a.z += f.z; a.w += f.w;
      }
    }
  }

  if (valid) {
    const float dd = dis[d0];
    const float4 b4 = ((const float4*)bias)[c];
    union { uint2 uu; __half2 h[2]; } pk;
    pk.h[0] = __floats2half2_rn(fmaxf(a.x * dd + b4.x, 0.f),
                                fmaxf(a.y * dd + b4.y, 0.f));
    pk.h[1] = __floats2half2_rn(fmaxf(a.z * dd + b4.z, 0.f),
                                fmaxf(a.w * dd + b4.w, 0.f));
    ((uint2*)O)[(long)d0 * 16 + c] = pk.uu;
  }
}

// ---------------- pooling ----------------

__global__ void logits_kernel(const float* __restrict__ clo, const float* __restrict__ Wc,
                              const float* __restrict__ bc, float* __restrict__ lb, int N) {
  int i = blockIdx.x * blockDim.x + threadIdx.x;
  if (i >= N) return;
  float s = bc[0];
#pragma unroll
  for (int k = 0; k < 8; ++k) s += clo[(long)i * 8 + k] * Wc[k];
  lb[i] = s;
}

__global__ __launch_bounds__(256) void pool_kernel(
    const __half* __restrict__ h3, const float* __restrict__ lb,
    const int* __restrict__ batch, const float* __restrict__ Wa1,
    const float* __restrict__ ba1, const float* __restrict__ Wa2,
    const float* __restrict__ ba2, float* __restrict__ out, int N) {
  __shared__ int sLo, sHi;
  __shared__ float red[256];
  __shared__ float Vs[4][64];
  __shared__ float sse[4];
  __shared__ float gv[64];
  __shared__ float am[16];
  const int g = blockIdx.x;
  const int t = threadIdx.x;
  if (t == 0) {
    int lo = 0, hi = N;
    while (lo < hi) { int mid = (lo + hi) >> 1; if (batch[mid] < g) lo = mid + 1; else hi = mid; }
    sLo = lo;
    lo = 0; hi = N;
    while (lo < hi) { int mid = (lo + hi) >> 1; if (batch[mid] < g + 1) lo = mid + 1; else hi = mid; }
    sHi = lo;
  }
  __syncthreads();
  const int lo = sLo, hi = sHi;

  float lm = -1e30f;
  for (int i = lo + t; i < hi; i += 256) lm = fmaxf(lm, lb[i]);
  red[t] = lm;
  __syncthreads();
  for (int s = 128; s > 0; s >>= 1) {
    if (t < s) red[t] = fmaxf(red[t], red[t + s]);
    __syncthreads();
  }
  const float m = red[0];

  const int f = t & 63, sub = t >> 6;
  float vacc = 0.f, seacc = 0.f;
  for (int i = lo + sub; i < hi; i += 4) {
    float e = expf(lb[i] - m);
    seacc += e;
    vacc += e * __half2float(h3[(long)i * 64 + f]);
  }
  Vs[sub][f] = vacc;
  if (f == 0) sse[sub] = seacc;
  __syncthreads();
  if (t < 64) {
    float se = sse[0] + sse[1] + sse[2] + sse[3];
    float v = Vs[0][f] + Vs[1][f] + Vs[2][f] + Vs[3][f];
    gv[f] = (se > 0.f) ? v / se : 0.f;
  }
  __syncthreads();
  if (t < 16) {
    float a = ba1[t];
#pragma unroll
    for (int k2 = 0; k2 < 64; ++k2) a += gv[k2] * Wa1[k2 * 16 + t];
    am[t] = a > 0.f ? a : 0.f;
  }
  __syncthreads();
  if (t == 0) {
    float o = ba2[0];
#pragma unroll
    for (int j = 0; j < 16; ++j) o += am[j] * Wa2[j];
    out[g] = o;
  }
}

// ---------------- launcher ----------------

extern "C" void kernel_launch(void* const* d_in, const int* in_sizes, int n_in,
                              void* d_out, int out_size, void* d_ws, size_t ws_size,
                              hipStream_t stream) {
  const float* x   = (const float*)d_in[0];
  const float* clo = (const float*)d_in[1];
  const float* W1  = (const float*)d_in[2];
  const float* b1  = (const float*)d_in[3];
  const float* W2  = (const float*)d_in[4];
  const float* b2  = (const float*)d_in[5];
  const float* W3  = (const float*)d_in[6];
  const float* b3  = (const float*)d_in[7];
  const float* Wc  = (const float*)d_in[8];
  const float* bc  = (const float*)d_in[9];
  const float* Wa1 = (const float*)d_in[10];
  const float* ba1 = (const float*)d_in[11];
  const float* Wa2 = (const float*)d_in[12];
  const float* ba2 = (const float*)d_in[13];
  const int* edge  = (const int*)d_in[14];
  const int* batch = (const int*)d_in[15];
  float* out = (float*)d_out;

  const int N = in_sizes[15];        // 100000
  const int E = in_sizes[14] / 2;    // 1600000
  const int G = out_size;            // 256
  const int NBKT = (N + BKT_NODES - 1) >> BKT_SHIFT;  // 782 (<=1024)
  const int NBLK = (E + EPB - 1) / EPB;               // 196 (<=256)

  const int* src = edge;
  const int* dst = edge + E;

  char* p = (char*)d_ws;
  auto alloc = [&](size_t bytes) -> char* {
    char* r = p;
    p += (bytes + 255) & ~(size_t)255;
    return r;
  };
  __half* tsbuf         = (__half*)alloc((size_t)N * 64 * sizeof(__half));
  __half* bufH          = (__half*)alloc((size_t)N * 64 * sizeof(__half));
  int*   csr_src        = (int*)  alloc((size_t)E * sizeof(int));
  unsigned int* grouped = (unsigned int*)alloc((size_t)E * sizeof(unsigned int));
  int*   hist           = (int*)  alloc((size_t)NBKT * NBLK * sizeof(int));
  int*   ebase          = (int*)  alloc((size_t)NBKT * NBLK * sizeof(int));
  int*   btot           = (int*)  alloc((size_t)NBKT * sizeof(int));
  int*   bbase          = (int*)  alloc((size_t)(NBKT + 1) * sizeof(int));
  int*   ends           = (int*)  alloc((size_t)N * sizeof(int));
  float* dis            = (float*)alloc((size_t)N * sizeof(float));
  float* lb             = (float*)alloc((size_t)N * sizeof(float));
  (void)ws_size; (void)n_in;

  block_hist_kernel<<<NBLK, 1024, 0, stream>>>(dst, hist, E, NBKT, NBLK);
  row_scan_kernel<<<NBKT, 256, 0, stream>>>(hist, ebase, btot, NBLK);
  bucket_scan_kernel<<<1, 1024, 0, stream>>>(btot, bbase, E, NBKT);
  group_kernel<<<NBLK, 1024, 0, stream>>>(src, dst, bbase, ebase, grouped, E, NBKT, NBLK);
  bucket_build_kernel<<<NBKT, 256, 0, stream>>>(grouped, bbase, csr_src, ends, dis, N);

  const int gN = (N + 255) / 256;
  const int gGemm = (N + 63) / 64;
  const int gAgg  = (N + 15) / 16;   // 16 nodes per 256-thread block

  gemm_mfma_kernel<128, float><<<gGemm, 256, 0, stream>>>(x, W1, dis, tsbuf, N);
  aggregate_kernel<<<gAgg, 256, 0, stream>>>(tsbuf, csr_src, ends, dis, b1, bufH, N);
  gemm_mfma_kernel<64, __half><<<gGemm, 256, 0, stream>>>(bufH, W2, dis, tsbuf, N);
  aggregate_kernel<<<gAgg, 256, 0, stream>>>(tsbuf, csr_src, ends, dis, b2, bufH, N);
  gemm_mfma_kernel<64, __half><<<gGemm, 256, 0, stream>>>(bufH, W3, dis, tsbuf, N);
  aggregate_kernel<<<gAgg, 256, 0, stream>>>(tsbuf, csr_src, ends, dis, b3, bufH, N);

  logits_kernel<<<gN, 256, 0, stream>>>(clo, Wc, bc, lb, N);
  pool_kernel<<<G, 256, 0, stream>>>(bufH, lb, batch, Wa1, ba1, Wa2, ba2, out, N);
}